// Round 10
// baseline (470.317 us; speedup 1.0000x reference)
//
#include <hip/hip_runtime.h>
#include <math.h>

#define BB 4
#define LL 1024
#define DD 1024
#define KK 20
#define CC 21
#define LC (LL * CC)          // 21504 floats per (b, i) output row-panel
#define NQ (LC / 4)           // 5376 float4 per panel

typedef float vf4   __attribute__((ext_vector_type(4)));   // native vec for NT store
typedef short bf16x8 __attribute__((ext_vector_type(8)));  // MFMA A/B frag (8 bf16)
typedef float f32x4  __attribute__((ext_vector_type(4)));  // MFMA C/D frag

__device__ __forceinline__ unsigned short f2bf(float f) {  // RNE f32->bf16
    unsigned int u = __builtin_bit_cast(unsigned int, f);
    u += 0x7FFFu + ((u >> 16) & 1u);
    return (unsigned short)(u >> 16);
}

__device__ __forceinline__ float wave_reduce_sum(float v) {
    #pragma unroll
    for (int off = 1; off < 64; off <<= 1)
        v += __shfl_xor(v, off, 64);
    return v;
}

// ---------------------------------------------------------------------------
// Kernel 0: blocks 0..839: zd[k,c], M[k,c]; blocks 840..863: Wcat bf16 [48][1024]
// ---------------------------------------------------------------------------
__global__ __launch_bounds__(64) void k0_zdM(
    const float* __restrict__ dic,
    const float* __restrict__ Wz_w, const float* __restrict__ Wz_b,
    const float* __restrict__ cs_w, const float* __restrict__ Wy_w,
    float* __restrict__ zd, float* __restrict__ M,
    unsigned short* __restrict__ Wcat)
{
    int blk = blockIdx.x;
    int lane = threadIdx.x;

    if (blk < 2 * KK * CC) {
        bool isM = (blk >= KK * CC);
        int e2 = isM ? blk - KK * CC : blk;
        int k = e2 / CC, c = e2 % CC;
        const float* a = dic + k * DD;
        const float* w = isM ? (cs_w + (size_t)c * (2 * DD) + DD) : (Wz_w + c * DD);
        float p = 0.f;
        #pragma unroll
        for (int i = 0; i < DD / 64; ++i) {
            int d = lane + 64 * i;
            p += a[d] * w[d];
        }
        p = wave_reduce_sum(p);
        if (lane == 0) {
            if (isM) M[e2] = p;
            else     zd[e2] = p + Wz_b[c];
        }
    } else {
        int e2 = blk - 2 * KK * CC;       // 0..23, each converts 2048 elems
        int base = e2 * 2048;
        #pragma unroll
        for (int t = 0; t < 32; ++t) {
            int i = base + lane + 64 * t;
            int c = i >> 10, k = i & 1023;
            float v;
            if (c < CC)          v = Wy_w[(size_t)c * DD + k];
            else if (c < 2 * CC) v = cs_w[(size_t)(c - CC) * (2 * DD) + k];
            else                 v = 0.f;
            Wcat[i] = f2bf(v);
        }
    }
}

// ---------------------------------------------------------------------------
// Kernel 1 (MFMA, DIAGNOSTIC rep): identical math, body repeated `rep` times.
// ---------------------------------------------------------------------------
__global__ __launch_bounds__(64) void k1_mfma(
    const float* __restrict__ x,
    const float* __restrict__ prior,
    const float* __restrict__ Wy_b, const float* __restrict__ cs_b,
    const unsigned short* __restrict__ Wcat,
    const float* __restrict__ zd, const float* __restrict__ M,
    float* __restrict__ ly_ws, float* __restrict__ lz_ws, int rep)
{
    const int lane = threadIdx.x;
    const int r0 = blockIdx.x * 16;

    __shared__ float zds[KK * CC];
    __shared__ float Ms[KK * CC];
    __shared__ float pr[KK];
    __shared__ float bias[2 * CC];      // [0..20]=Wy_b, [21..41]=cs_b
    __shared__ float yT[16][49];

    for (int i = lane; i < KK * CC; i += 64) { zds[i] = zd[i]; Ms[i] = M[i]; }
    if (lane < KK) pr[lane] = prior[lane];
    if (lane < CC) { bias[lane] = Wy_b[lane]; bias[CC + lane] = cs_b[lane]; }

    const int fr = lane & 15;           // frag row (A) / col (B,D) index
    const int kg = lane >> 4;           // k-group 0..3

    const float*          xp  = x    + (size_t)(r0 + fr) * DD + kg * 8;
    const unsigned short* w0p = Wcat + (size_t)(fr +  0) * DD + kg * 8;
    const unsigned short* w1p = Wcat + (size_t)(fr + 16) * DD + kg * 8;
    const unsigned short* w2p = Wcat + (size_t)(fr + 32) * DD + kg * 8;

    for (int rp = 0; rp < rep; ++rp) {
        asm volatile("" ::: "memory");      // defeat cross-rep CSE

        f32x4 acc0 = {0.f, 0.f, 0.f, 0.f};
        f32x4 acc1 = {0.f, 0.f, 0.f, 0.f};
        f32x4 acc2 = {0.f, 0.f, 0.f, 0.f};

        #pragma unroll 4
        for (int ks = 0; ks < 32; ++ks) {
            float4 a0 = *reinterpret_cast<const float4*>(xp + ks * 32);
            float4 a1 = *reinterpret_cast<const float4*>(xp + ks * 32 + 4);
            bf16x8 af;
            af[0] = (short)f2bf(a0.x); af[1] = (short)f2bf(a0.y);
            af[2] = (short)f2bf(a0.z); af[3] = (short)f2bf(a0.w);
            af[4] = (short)f2bf(a1.x); af[5] = (short)f2bf(a1.y);
            af[6] = (short)f2bf(a1.z); af[7] = (short)f2bf(a1.w);
            bf16x8 b0 = *reinterpret_cast<const bf16x8*>(w0p + ks * 32);
            bf16x8 b1 = *reinterpret_cast<const bf16x8*>(w1p + ks * 32);
            bf16x8 b2 = *reinterpret_cast<const bf16x8*>(w2p + ks * 32);
            acc0 = __builtin_amdgcn_mfma_f32_16x16x32_bf16(af, b0, acc0, 0, 0, 0);
            acc1 = __builtin_amdgcn_mfma_f32_16x16x32_bf16(af, b1, acc1, 0, 0, 0);
            acc2 = __builtin_amdgcn_mfma_f32_16x16x32_bf16(af, b2, acc2, 0, 0, 0);
        }

        __syncthreads();                    // protect yT across reps (WAR)
        #pragma unroll
        for (int j = 0; j < 4; ++j) {
            yT[kg * 4 + j][fr]      = acc0[j];
            yT[kg * 4 + j][16 + fr] = acc1[j];
            yT[kg * 4 + j][32 + fr] = acc2[j];
        }
        __syncthreads();

        const float* f = yT[fr];
        const float scale = 0.21821789023599238f;   // 1/sqrt(21)
        float s[KK];
        float m = -1e30f;
        #pragma unroll
        for (int k = 0; k < KK; ++k) {
            float t = 0.f;
            #pragma unroll
            for (int c = 0; c < CC; ++c) t += (f[c] + bias[c]) * zds[k * CC + c];
            s[k] = t * scale;
            m = fmaxf(m, s[k]);
        }
        float sum = 0.f;
        #pragma unroll
        for (int k = 0; k < KK; ++k) { s[k] = expf(s[k] - m); sum += s[k]; }
        float inv = 1.f / sum;
        float wk[KK];
        #pragma unroll
        for (int k = 0; k < KK; ++k) wk[k] = s[k] * inv * pr[k];

        size_t rr = (size_t)(r0 + fr);
        for (int c = kg; c < CC; c += 4) {
            float lzv = bias[CC + c];                   // cs_b
            #pragma unroll
            for (int k = 0; k < KK; ++k) lzv += wk[k] * Ms[k * CC + c];
            ly_ws[rr * CC + c] = f[CC + c];             // yT col 21+c
            lz_ws[rr * CC + c] = lzv;
        }
    }
}

// ---------------------------------------------------------------------------
// Kernel 2 (DIAGNOSTIC rep): store sweep repeated `rep` times.
// ---------------------------------------------------------------------------
__global__ __launch_bounds__(512) void k2_outer(
    const float* __restrict__ ly_ws, const float* __restrict__ lz_ws,
    float* __restrict__ out, int rep)
{
    int tid = threadIdx.x;
    int blk = blockIdx.x;               // 0..1023
    int b  = blk >> 8;                  // 256 blocks per image
    int i0 = (blk & 255) << 2;          // * 4 panels

    __shared__ vf4 lyp4[4 * CC];
    {
        float* lyp = reinterpret_cast<float*>(lyp4);
        if (tid < 4 * 84) {
            int i = tid / 84, f = tid % 84;
            lyp[i * 84 + f] = ly_ws[(size_t)(b * LL + i0 + i) * CC + (f % 21)];
        }
    }

    const float* lzp = lz_ws + (size_t)b * LC;
    vf4 lzv[11];
    #pragma unroll
    for (int it = 0; it < 11; ++it) {
        int idx = tid + it * 512;
        if (idx < NQ) {
            lzv[it] = *reinterpret_cast<const vf4*>(lzp + (size_t)idx * 4);
        } else {
            lzv[it] = (vf4){0.f, 0.f, 0.f, 0.f};
        }
    }
    __syncthreads();

    int g0 = tid % 21;                  // (tid + it*512) % 21 steps by +8 mod 21

    for (int rp = 0; rp < rep; ++rp) {
        asm volatile("" ::: "memory");      // defeat cross-rep store elision
        #pragma unroll
        for (int i = 0; i < 4; ++i) {
            float* op = out + (size_t)(b * LL + i0 + i) * LC;
            const vf4* lyp_i = lyp4 + i * CC;
            int g = g0;
            #pragma unroll
            for (int it = 0; it < 11; ++it) {
                int idx = tid + it * 512;
                if (idx < NQ) {
                    vf4 o = lzv[it] + lyp_i[g];
                    __builtin_nontemporal_store(o, reinterpret_cast<vf4*>(op + (size_t)idx * 4));
                }
                g += 8; if (g >= 21) g -= 21;
            }
        }
    }
}

extern "C" void kernel_launch(void* const* d_in, const int* in_sizes, int n_in,
                              void* d_out, int out_size, void* d_ws, size_t ws_size,
                              hipStream_t stream)
{
    const float* x     = (const float*)d_in[0];
    const float* dic   = (const float*)d_in[1];
    const float* prior = (const float*)d_in[2];
    const float* Wy_w  = (const float*)d_in[3];
    const float* Wy_b  = (const float*)d_in[4];
    const float* Wz_w  = (const float*)d_in[5];
    const float* Wz_b  = (const float*)d_in[6];
    const float* cs_w  = (const float*)d_in[7];
    const float* cs_b  = (const float*)d_in[8];
    float* out = (float*)d_out;

    float* ws = (float*)d_ws;
    float* zd = ws;                       // 420 floats
    float* M  = ws + 512;                 // 420 floats
    float* ly = ws + 1024;                // B*L*C = 86016 floats
    float* lz = ly + BB * LL * CC;        // 86016 floats
    unsigned short* Wcat = (unsigned short*)(ws + 1024 + 2 * BB * LL * CC);  // 48*1024 bf16

    k0_zdM <<<dim3(2 * KK * CC + 24), dim3(64),  0, stream>>>(dic, Wz_w, Wz_b, cs_w, Wy_w,
                                                              zd, M, Wcat);
    k1_mfma<<<dim3(BB * LL / 16),     dim3(64),  0, stream>>>(x, prior, Wy_b, cs_b, Wcat,
                                                              zd, M, ly, lz, 8);
    k2_outer<<<dim3(BB * LL / 4),     dim3(512), 0, stream>>>(ly, lz, out, 4);
}

// Round 11
// 103.565 us; speedup vs baseline: 4.5413x; 4.5413x over previous
//
#include <hip/hip_runtime.h>
#include <math.h>

#define BB 4
#define LL 1024
#define DD 1024
#define KK 20
#define CC 21
#define LC (LL * CC)          // 21504 floats per (b, i) output row-panel
#define NQ (LC / 4)           // 5376 float4 per panel

typedef float vf4   __attribute__((ext_vector_type(4)));
typedef short bf16x8 __attribute__((ext_vector_type(8)));  // MFMA A/B frag (8 bf16)
typedef float f32x4  __attribute__((ext_vector_type(4)));  // MFMA C/D frag

__device__ __forceinline__ unsigned short f2bf(float f) {  // RNE f32->bf16
    unsigned int u = __builtin_bit_cast(unsigned int, f);
    u += 0x7FFFu + ((u >> 16) & 1u);
    return (unsigned short)(u >> 16);
}

__device__ __forceinline__ float wave_reduce_sum(float v) {
    #pragma unroll
    for (int off = 1; off < 64; off <<= 1)
        v += __shfl_xor(v, off, 64);
    return v;
}

// ---------------------------------------------------------------------------
// Kernel 0: blocks 0..839: zd[k,c], M[k,c]; blocks 840..863: Wcat bf16 [48][1024]
// ---------------------------------------------------------------------------
__global__ __launch_bounds__(64) void k0_zdM(
    const float* __restrict__ dic,
    const float* __restrict__ Wz_w, const float* __restrict__ Wz_b,
    const float* __restrict__ cs_w, const float* __restrict__ Wy_w,
    float* __restrict__ zd, float* __restrict__ M,
    unsigned short* __restrict__ Wcat)
{
    int blk = blockIdx.x;
    int lane = threadIdx.x;

    if (blk < 2 * KK * CC) {
        bool isM = (blk >= KK * CC);
        int e2 = isM ? blk - KK * CC : blk;
        int k = e2 / CC, c = e2 % CC;
        const float* a = dic + k * DD;
        const float* w = isM ? (cs_w + (size_t)c * (2 * DD) + DD) : (Wz_w + c * DD);
        float p = 0.f;
        #pragma unroll
        for (int i = 0; i < DD / 64; ++i) {
            int d = lane + 64 * i;
            p += a[d] * w[d];
        }
        p = wave_reduce_sum(p);
        if (lane == 0) {
            if (isM) M[e2] = p;
            else     zd[e2] = p + Wz_b[c];
        }
    } else {
        int e2 = blk - 2 * KK * CC;       // 0..23, each converts 2048 elems
        int base = e2 * 2048;
        #pragma unroll
        for (int t = 0; t < 32; ++t) {
            int i = base + lane + 64 * t;
            int c = i >> 10, k = i & 1023;
            float v;
            if (c < CC)          v = Wy_w[(size_t)c * DD + k];
            else if (c < 2 * CC) v = cs_w[(size_t)(c - CC) * (2 * DD) + k];
            else                 v = 0.f;
            Wcat[i] = f2bf(v);
        }
    }
}

// ---------------------------------------------------------------------------
// Kernel 1 (MFMA, split-K x4): 256 blocks x 4 waves. Wave w computes the
// 16x48 tile's partial over K in [256w, 256w+256) via 3x mfma_16x16x32_bf16,
// dumps D frags to pacc[w][16][49], cross-wave reduce, wave-0 epilogue
// (softmax + lz, identical to the R9-verified code).
// ---------------------------------------------------------------------------
__global__ __launch_bounds__(256) void k1_mfma(
    const float* __restrict__ x,
    const float* __restrict__ prior,
    const float* __restrict__ Wy_b, const float* __restrict__ cs_b,
    const unsigned short* __restrict__ Wcat,
    const float* __restrict__ zd, const float* __restrict__ M,
    float* __restrict__ ly_ws, float* __restrict__ lz_ws)
{
    const int tid  = threadIdx.x;
    const int wid  = tid >> 6;
    const int lane = tid & 63;
    const int fr   = lane & 15;         // A row / B row / D col index
    const int kg   = lane >> 4;         // k-group 0..3
    const int r0   = blockIdx.x * 16;

    __shared__ float zds[KK * CC];
    __shared__ float Ms[KK * CC];
    __shared__ float pr[KK];
    __shared__ float bias[2 * CC];      // [0..20]=Wy_b, [21..41]=cs_b
    __shared__ float pacc[4 * 16 * 49]; // [w][m][col], row stride 49

    for (int i = tid; i < KK * CC; i += 256) { zds[i] = zd[i]; Ms[i] = M[i]; }
    if (tid < KK) pr[tid] = prior[tid];
    if (tid < CC) { bias[tid] = Wy_b[tid]; bias[CC + tid] = cs_b[tid]; }

    const int kbase = wid * 256;        // this wave's K-quarter
    const float*          xp  = x    + (size_t)(r0 + fr) * DD + kbase + kg * 8;
    const unsigned short* w0p = Wcat + (size_t)(fr +  0) * DD + kbase + kg * 8;
    const unsigned short* w1p = Wcat + (size_t)(fr + 16) * DD + kbase + kg * 8;
    const unsigned short* w2p = Wcat + (size_t)(fr + 32) * DD + kbase + kg * 8;

    f32x4 acc0 = {0.f, 0.f, 0.f, 0.f};
    f32x4 acc1 = {0.f, 0.f, 0.f, 0.f};
    f32x4 acc2 = {0.f, 0.f, 0.f, 0.f};

    #pragma unroll
    for (int ks = 0; ks < 8; ++ks) {
        float4 a0 = *reinterpret_cast<const float4*>(xp + ks * 32);
        float4 a1 = *reinterpret_cast<const float4*>(xp + ks * 32 + 4);
        bf16x8 af;
        af[0] = (short)f2bf(a0.x); af[1] = (short)f2bf(a0.y);
        af[2] = (short)f2bf(a0.z); af[3] = (short)f2bf(a0.w);
        af[4] = (short)f2bf(a1.x); af[5] = (short)f2bf(a1.y);
        af[6] = (short)f2bf(a1.z); af[7] = (short)f2bf(a1.w);
        bf16x8 b0 = *reinterpret_cast<const bf16x8*>(w0p + ks * 32);
        bf16x8 b1 = *reinterpret_cast<const bf16x8*>(w1p + ks * 32);
        bf16x8 b2 = *reinterpret_cast<const bf16x8*>(w2p + ks * 32);
        acc0 = __builtin_amdgcn_mfma_f32_16x16x32_bf16(af, b0, acc0, 0, 0, 0);
        acc1 = __builtin_amdgcn_mfma_f32_16x16x32_bf16(af, b1, acc1, 0, 0, 0);
        acc2 = __builtin_amdgcn_mfma_f32_16x16x32_bf16(af, b2, acc2, 0, 0, 0);
    }

    // D frags -> pacc[wid]: m = kg*4+j, cols fr / 16+fr / 32+fr
    #pragma unroll
    for (int j = 0; j < 4; ++j) {
        float* pw = pacc + (wid * 16 + kg * 4 + j) * 49;
        pw[fr]      = acc0[j];
        pw[16 + fr] = acc1[j];
        pw[32 + fr] = acc2[j];
    }
    __syncthreads();

    // cross-wave reduce: 768 outputs, thread-owned, in-place into pacc[w=0]
    #pragma unroll
    for (int p = 0; p < 3; ++p) {
        int o = tid + p * 256;          // 0..767
        int row = o / 48, col = o % 48;
        float s = pacc[row * 49 + col]
                + pacc[(16 + row) * 49 + col]
                + pacc[(32 + row) * 49 + col]
                + pacc[(48 + row) * 49 + col];
        pacc[row * 49 + col] = s;       // each slot read+written by exactly one thread
    }
    __syncthreads();

    // wave-0 epilogue: softmax for row fr (4-way redundant over kg), lz for c=kg::4
    if (tid < 64) {
        const float* f = pacc + fr * 49;
        const float scale = 0.21821789023599238f;   // 1/sqrt(21)
        float s[KK];
        float m = -1e30f;
        #pragma unroll
        for (int k = 0; k < KK; ++k) {
            float t = 0.f;
            #pragma unroll
            for (int c = 0; c < CC; ++c) t += (f[c] + bias[c]) * zds[k * CC + c];
            s[k] = t * scale;
            m = fmaxf(m, s[k]);
        }
        float sum = 0.f;
        #pragma unroll
        for (int k = 0; k < KK; ++k) { s[k] = expf(s[k] - m); sum += s[k]; }
        float inv = 1.f / sum;
        float wk[KK];
        #pragma unroll
        for (int k = 0; k < KK; ++k) wk[k] = s[k] * inv * pr[k];

        size_t rr = (size_t)(r0 + fr);
        for (int c = kg; c < CC; c += 4) {
            float lzv = bias[CC + c];                   // cs_b
            #pragma unroll
            for (int k = 0; k < KK; ++k) lzv += wk[k] * Ms[k * CC + c];
            ly_ws[rr * CC + c] = f[CC + c];             // cols 21..41 = ly
            lz_ws[rr * CC + c] = lzv;
        }
    }
}

// ---------------------------------------------------------------------------
// Kernel 2: outer-sum write — regular stores (NT was a 30% BW regression).
// ---------------------------------------------------------------------------
__global__ __launch_bounds__(512) void k2_outer(
    const float* __restrict__ ly_ws, const float* __restrict__ lz_ws,
    float* __restrict__ out)
{
    int tid = threadIdx.x;
    int blk = blockIdx.x;               // 0..1023
    int b  = blk >> 8;                  // 256 blocks per image
    int i0 = (blk & 255) << 2;          // * 4 panels

    __shared__ vf4 lyp4[4 * CC];
    {
        float* lyp = reinterpret_cast<float*>(lyp4);
        if (tid < 4 * 84) {
            int i = tid / 84, f = tid % 84;
            lyp[i * 84 + f] = ly_ws[(size_t)(b * LL + i0 + i) * CC + (f % 21)];
        }
    }

    const float* lzp = lz_ws + (size_t)b * LC;
    vf4 lzv[11];
    #pragma unroll
    for (int it = 0; it < 11; ++it) {
        int idx = tid + it * 512;
        if (idx < NQ) {
            lzv[it] = *reinterpret_cast<const vf4*>(lzp + (size_t)idx * 4);
        } else {
            lzv[it] = (vf4){0.f, 0.f, 0.f, 0.f};
        }
    }
    __syncthreads();

    int g0 = tid % 21;                  // (tid + it*512) % 21 steps by +8 mod 21

    #pragma unroll
    for (int i = 0; i < 4; ++i) {
        float* op = out + (size_t)(b * LL + i0 + i) * LC;
        const vf4* lyp_i = lyp4 + i * CC;
        int g = g0;
        #pragma unroll
        for (int it = 0; it < 11; ++it) {
            int idx = tid + it * 512;
            if (idx < NQ) {
                *reinterpret_cast<vf4*>(op + (size_t)idx * 4) = lzv[it] + lyp_i[g];
            }
            g += 8; if (g >= 21) g -= 21;
        }
    }
}

extern "C" void kernel_launch(void* const* d_in, const int* in_sizes, int n_in,
                              void* d_out, int out_size, void* d_ws, size_t ws_size,
                              hipStream_t stream)
{
    const float* x     = (const float*)d_in[0];
    const float* dic   = (const float*)d_in[1];
    const float* prior = (const float*)d_in[2];
    const float* Wy_w  = (const float*)d_in[3];
    const float* Wy_b  = (const float*)d_in[4];
    const float* Wz_w  = (const float*)d_in[5];
    const float* Wz_b  = (const float*)d_in[6];
    const float* cs_w  = (const float*)d_in[7];
    const float* cs_b  = (const float*)d_in[8];
    float* out = (float*)d_out;

    float* ws = (float*)d_ws;
    float* zd = ws;                       // 420 floats
    float* M  = ws + 512;                 // 420 floats
    float* ly = ws + 1024;                // B*L*C = 86016 floats
    float* lz = ly + BB * LL * CC;        // 86016 floats
    unsigned short* Wcat = (unsigned short*)(ws + 1024 + 2 * BB * LL * CC);  // 48*1024 bf16

    k0_zdM <<<dim3(2 * KK * CC + 24), dim3(64),  0, stream>>>(dic, Wz_w, Wz_b, cs_w, Wy_w,
                                                              zd, M, Wcat);
    k1_mfma<<<dim3(BB * LL / 16),     dim3(256), 0, stream>>>(x, prior, Wy_b, cs_b, Wcat,
                                                              zd, M, ly, lz);
    k2_outer<<<dim3(BB * LL / 4),     dim3(512), 0, stream>>>(ly, lz, out);
}